// Round 19
// baseline (222.693 us; speedup 1.0000x reference)
//
#include <hip/hip_runtime.h>

#define N_NODES 50000
#define N_EDGES 800000

#define SCAN_BLOCKS ((N_NODES + 255) / 256) // 196

static inline size_t alignUp(size_t x, size_t a) { return (x + a - 1) & ~(a - 1); }

// scalar-element ext vector types (R7: HIP vector classes rejected by builtins)
typedef _Float16 h2 __attribute__((ext_vector_type(2)));
typedef _Float16 h4 __attribute__((ext_vector_type(4)));
typedef _Float16 h8 __attribute__((ext_vector_type(8)));
typedef float    fx4 __attribute__((ext_vector_type(4)));

// ---------------- init: zero degree counters + fp16 W^T prep (fused) ----

__global__ void k_init(int* __restrict__ count, const float* __restrict__ W1,
                       const float* __restrict__ W2, const float* __restrict__ W3,
                       _Float16* __restrict__ W1T, _Float16* __restrict__ W2T,
                       _Float16* __restrict__ W3T) {
    int i = blockIdx.x * 256 + threadIdx.x;
    if (i < N_NODES) count[i] = 0;
    if (i < 8192) {            // W1[64][128] -> W1T[128][64]
        int n = i >> 6, k = i & 63;
        W1T[i] = (_Float16)W1[k * 128 + n];
    } else if (i < 24576) {    // W2[128][128] -> W2T[128][128]
        int j = i - 8192; int n = j >> 7, k = j & 127;
        W2T[j] = (_Float16)W2[k * 128 + n];
    } else if (i < 32768) {    // W3[128][64] -> W3T[64][128]
        int j = i - 24576; int n = j >> 7, k = j & 127;
        W3T[j] = (_Float16)W3[k * 64 + n];
    }
}

// ---------------- CSR build (R14 rank-split; R16 4-edge form) ----

__global__ void k_count4(const int* __restrict__ row, int* __restrict__ count,
                         int* __restrict__ rank, int* __restrict__ pad) {
    int i = blockIdx.x * 256 + threadIdx.x;
    if (i < 64) pad[i] = 0;
    if (i < N_EDGES / 4) {
        int4 r = reinterpret_cast<const int4*>(row)[i];
        int k0 = atomicAdd(&count[r.x], 1);
        int k1 = atomicAdd(&count[r.y], 1);
        int k2 = atomicAdd(&count[r.z], 1);
        int k3 = atomicAdd(&count[r.w], 1);
        reinterpret_cast<int4*>(rank)[i] = make_int4(k0, k1, k2, k3);
    }
}

// Fused 3-in-1 scan (R18-proven): each block redundantly computes its prefix
// base over counts[0 .. b*256) (L2-hot), then scans its own chunk.
__global__ void k_scan_fused(const int* __restrict__ count, int* __restrict__ offsets,
                             float* __restrict__ dinv) {
    __shared__ int s[256];
    int t = threadIdx.x, b = blockIdx.x;
    int partial = 0;
    for (int c = 0; c < b; ++c) partial += count[c * 256 + t];
    s[t] = partial;
    __syncthreads();
    for (int off = 128; off > 0; off >>= 1) {
        if (t < off) s[t] += s[t + off];
        __syncthreads();
    }
    int base = s[0];
    __syncthreads();
    int i = b * 256 + t;
    int v = (i < N_NODES) ? count[i] : 0;
    s[t] = v;
    __syncthreads();
    for (int off = 1; off < 256; off <<= 1) {
        int add = (t >= off) ? s[t - off] : 0;
        __syncthreads();
        s[t] += add;
        __syncthreads();
    }
    if (i < N_NODES) {
        offsets[i] = base + s[t] - v;
        dinv[i]    = rsqrtf((float)(v + 1)); // +1 self-loop; always > 0
    }
}

// atomic-free scatter + fused fp16 feature prescale
__global__ void k_scatter(const int* __restrict__ row, const int* __restrict__ col,
                          const int* __restrict__ offsets, const int* __restrict__ rank,
                          int* __restrict__ csr_col,
                          const float* __restrict__ feat, const float* __restrict__ dinv,
                          _Float16* __restrict__ featS) {
    int e = blockIdx.x * 256 + threadIdx.x;
    if (e < N_EDGES) {
        int node = e >> 4;
        float d = dinv[node];
        float4 v = reinterpret_cast<const float4*>(feat)[e];
        h4 hv = {(_Float16)(v.x * d), (_Float16)(v.y * d),
                 (_Float16)(v.z * d), (_Float16)(v.w * d)};
        reinterpret_cast<h4*>(featS)[e] = hv;
        int r = row[e];
        csr_col[offsets[r] + rank[e]] = col[e];
    }
}

// ---------------- Aggregation over PRE-SCALED fp16 rows (R17-proven) ----------
// out[i] = dinv_i * ( h'[i] + sum_c h'[c] ) (+bias); fp32 accumulate.
// One node per WAVE, independent retirement (R18 lesson: no barrier coupling).

// F=128: 64 lanes x h2 = one 256B row per instruction; 8 edges per batch.
template <bool BIAS, bool HOUT>
__global__ __launch_bounds__(256) void k_agg128(const _Float16* __restrict__ hs, void* __restrict__ out,
        const int* __restrict__ csr_col, const int* __restrict__ offsets,
        const int* __restrict__ count, const float* __restrict__ dinv,
        const float* __restrict__ bias) {
    int lane = threadIdx.x & 63;
    int node = blockIdx.x * 4 + (threadIdx.x >> 6);
    const char* base = (const char*)hs;
    uint32_t lo = (uint32_t)lane << 2;

    float ax[8], ay[8];
#pragma unroll
    for (int u = 0; u < 8; u++) { ax[u] = 0.f; ay[u] = 0.f; }

    int n = count[node];
    const int* cp = csr_col + offsets[node];

    int e = 0;
    for (; e + 8 <= n; e += 8) {
        int c[8];
#pragma unroll
        for (int u = 0; u < 8; u++) c[u] = cp[e + u];
#pragma unroll
        for (int u = 0; u < 8; u++) {
            h2 v = *reinterpret_cast<const h2*>(base + (((uint32_t)c[u] << 8) + lo));
            ax[u] += (float)v.x; ay[u] += (float)v.y;
        }
    }
    if (e < n) {
        int c[8];
#pragma unroll
        for (int u = 0; u < 8; u++) c[u] = cp[e + u]; // padded, safe
#pragma unroll
        for (int u = 0; u < 8; u++) {
            h2 v = *reinterpret_cast<const h2*>(base + (((uint32_t)c[u] << 8) + lo));
            if (e + u < n) { ax[u] += (float)v.x; ay[u] += (float)v.y; }
        }
    }

    float sx = 0.f, sy = 0.f;
#pragma unroll
    for (int u = 0; u < 8; u++) { sx += ax[u]; sy += ay[u]; }
    h2 self = *reinterpret_cast<const h2*>(base + (((uint32_t)node << 8) + lo));
    float d = dinv[node];
    float ox = (sx + (float)self.x) * d, oy = (sy + (float)self.y) * d;
    if (BIAS) { ox += bias[2 * lane]; oy += bias[2 * lane + 1]; }
    if constexpr (HOUT) {
        h2 hv = {(_Float16)ox, (_Float16)oy};
        reinterpret_cast<h2*>(out)[(size_t)node * 64 + lane] = hv;
    } else {
        reinterpret_cast<float2*>(out)[(size_t)node * 64 + lane] = make_float2(ox, oy);
    }
}

// F=64: 16 lanes x h4 = one 128B row, 4 edges per instruction -> 32/batch.
template <bool BIAS, bool HOUT>
__global__ __launch_bounds__(256) void k_agg64(const _Float16* __restrict__ hs, void* __restrict__ out,
        const int* __restrict__ csr_col, const int* __restrict__ offsets,
        const int* __restrict__ count, const float* __restrict__ dinv,
        const float* __restrict__ bias) {
    int lane = threadIdx.x & 63;
    int node = blockIdx.x * 4 + (threadIdx.x >> 6);
    int q = lane >> 4;
    int f4 = lane & 15;
    const char* base = (const char*)hs;
    uint32_t fo = (uint32_t)f4 << 3;

    int n = __builtin_amdgcn_readfirstlane(count[node]);
    int start = __builtin_amdgcn_readfirstlane(offsets[node]);
    const int* cp = csr_col + start;

    float4 a0 = make_float4(0.f, 0.f, 0.f, 0.f);
    float4 a1 = make_float4(0.f, 0.f, 0.f, 0.f);

    int e = 0;
    for (; e + 32 <= n; e += 32) {
        int c[8];
#pragma unroll
        for (int u = 0; u < 8; u++) c[u] = cp[e + 4 * u + q];
        h4 v[8];
#pragma unroll
        for (int u = 0; u < 8; u++)
            v[u] = *reinterpret_cast<const h4*>(base + (((uint32_t)c[u] << 7) + fo));
#pragma unroll
        for (int u = 0; u < 8; u += 2) {
            a0.x += (float)v[u].x; a0.y += (float)v[u].y;
            a0.z += (float)v[u].z; a0.w += (float)v[u].w;
            a1.x += (float)v[u+1].x; a1.y += (float)v[u+1].y;
            a1.z += (float)v[u+1].z; a1.w += (float)v[u+1].w;
        }
    }
    if (e < n) {
        int c[8];
#pragma unroll
        for (int u = 0; u < 8; u++) c[u] = cp[e + 4 * u + q]; // padded, safe
        h4 v[8];
#pragma unroll
        for (int u = 0; u < 8; u++)
            v[u] = *reinterpret_cast<const h4*>(base + (((uint32_t)c[u] << 7) + fo));
#pragma unroll
        for (int u = 0; u < 8; u++) {
            if (e + 4 * u + q < n) {
                a0.x += (float)v[u].x; a0.y += (float)v[u].y;
                a0.z += (float)v[u].z; a0.w += (float)v[u].w;
            }
        }
    }

    float sx = a0.x + a1.x, sy = a0.y + a1.y, sz = a0.z + a1.z, sw = a0.w + a1.w;
    sx += __shfl_xor(sx, 16); sy += __shfl_xor(sy, 16);
    sz += __shfl_xor(sz, 16); sw += __shfl_xor(sw, 16);
    sx += __shfl_xor(sx, 32); sy += __shfl_xor(sy, 32);
    sz += __shfl_xor(sz, 32); sw += __shfl_xor(sw, 32);
    if (q == 0) {
        h4 self = *reinterpret_cast<const h4*>(base + (((uint32_t)node << 7) + fo));
        float d = dinv[node];
        float ox = (sx + (float)self.x) * d, oy = (sy + (float)self.y) * d;
        float oz = (sz + (float)self.z) * d, ow = (sw + (float)self.w) * d;
        if (BIAS) {
            float4 bv = *reinterpret_cast<const float4*>(&bias[f4 * 4]);
            ox += bv.x; oy += bv.y; oz += bv.z; ow += bv.w;
        }
        if constexpr (HOUT) {
            h4 hv = {(_Float16)ox, (_Float16)oy, (_Float16)oz, (_Float16)ow};
            *reinterpret_cast<h4*>((char*)out + (((uint32_t)node << 7) + fo)) = hv;
        } else {
            *reinterpret_cast<float4*>((char*)out + ((uint32_t)node << 8) + (fo << 1)) =
                make_float4(ox, oy, oz, ow);
        }
    }
}

// ---------------- MFMA GEMM (layer 1) — R17-proven ----------------

template <int K, int NOUT, bool RELU, bool BIAS, bool SCALE>
__global__ __launch_bounds__(256) void k_gemm_mfma(const _Float16* __restrict__ x,
        const _Float16* __restrict__ WT, const float* __restrict__ bias,
        const float* __restrict__ dinv, _Float16* __restrict__ out, int nrows) {
    constexpr int NB = NOUT / 16;
    int l = threadIdx.x & 63;
    int w = threadIdx.x >> 6;
    int lm = l & 15;
    int kb = (l >> 4) * 8;
    int row0 = blockIdx.x * 64 + w * 16;

    int arow = row0 + lm;
    if (arow >= nrows) arow = nrows - 1;

    fx4 acc[NB] = {};

#pragma unroll
    for (int kk = 0; kk < K / 32; ++kk) {
        h8 a = *reinterpret_cast<const h8*>(x + (size_t)arow * K + kk * 32 + kb);
#pragma unroll
        for (int n = 0; n < NB; ++n) {
            h8 b = *reinterpret_cast<const h8*>(WT + (size_t)(n * 16 + lm) * K + kk * 32 + kb);
            acc[n] = __builtin_amdgcn_mfma_f32_16x16x32_f16(a, b, acc[n], 0, 0, 0);
        }
    }

    int rbase = row0 + (l >> 4) * 4;
    float dv[4];
#pragma unroll
    for (int t = 0; t < 4; ++t) {
        int gr = rbase + t;
        dv[t] = SCALE ? dinv[(gr < nrows) ? gr : (nrows - 1)] : 1.f;
    }
#pragma unroll
    for (int n = 0; n < NB; ++n) {
        float bvn = BIAS ? bias[n * 16 + lm] : 0.f;
#pragma unroll
        for (int t = 0; t < 4; ++t) {
            int gr = rbase + t;
            if (gr >= nrows) continue;
            float v = acc[n][t] + bvn;
            if (RELU) v = fmaxf(v, 0.f);
            v *= dv[t];
            out[(size_t)gr * NOUT + n * 16 + lm] = (_Float16)v;
        }
    }
}

// ---------------- Fused GEMM2+GEMM3 (R19) ----------------
// H3 = fp16(dinv .* ( relu(A2@W2+b2) @ W3 )). GEMM3 row r needs only X2
// row r, computed by the SAME wave -> X2 tile passes through a per-wave LDS
// region (16 rows x 128 cols, stride 136h). All LDS data is written and read
// by one wave: no __syncthreads, no cross-wave tail (R18 lesson). Numerics
// identical to R17 (same fp16 rounding point for X2).

__global__ __launch_bounds__(256) void k_gemm23(const _Float16* __restrict__ x,
        const _Float16* __restrict__ W2T, const float* __restrict__ b2,
        const _Float16* __restrict__ W3T, const float* __restrict__ dinv,
        _Float16* __restrict__ out, int nrows) {
    __shared__ _Float16 xt[4][16 * 136];
    int l = threadIdx.x & 63;
    int w = threadIdx.x >> 6;
    int lm = l & 15;
    int kb = (l >> 4) * 8;
    int row0 = blockIdx.x * 64 + w * 16;

    int arow = row0 + lm;
    if (arow >= nrows) arow = nrows - 1;

    // GEMM2: 16 rows x 128 cols, K=128
    fx4 acc[8] = {};
#pragma unroll
    for (int kk = 0; kk < 4; ++kk) {
        h8 a = *reinterpret_cast<const h8*>(x + (size_t)arow * 128 + kk * 32 + kb);
#pragma unroll
        for (int n = 0; n < 8; ++n) {
            h8 b = *reinterpret_cast<const h8*>(W2T + (size_t)(n * 16 + lm) * 128 + kk * 32 + kb);
            acc[n] = __builtin_amdgcn_mfma_f32_16x16x32_f16(a, b, acc[n], 0, 0, 0);
        }
    }
    // epilogue -> fp16 X2 tile in LDS (C layout: col=lm, row=(l>>4)*4+t)
    int rloc = (l >> 4) * 4;
#pragma unroll
    for (int n = 0; n < 8; ++n) {
        float bv = b2[n * 16 + lm];
#pragma unroll
        for (int t = 0; t < 4; ++t) {
            float v = fmaxf(acc[n][t] + bv, 0.f);
            xt[w][(rloc + t) * 136 + n * 16 + lm] = (_Float16)v;
        }
    }
    // same-wave LDS read-after-write: compiler inserts lgkmcnt; no barrier.

    // GEMM3: same 16 rows x 64 cols, K=128, A from LDS
    fx4 acc3[4] = {};
#pragma unroll
    for (int kk = 0; kk < 4; ++kk) {
        h8 a = *reinterpret_cast<const h8*>(&xt[w][lm * 136 + kk * 32 + kb]);
#pragma unroll
        for (int n = 0; n < 4; ++n) {
            h8 b = *reinterpret_cast<const h8*>(W3T + (size_t)(n * 16 + lm) * 128 + kk * 32 + kb);
            acc3[n] = __builtin_amdgcn_mfma_f32_16x16x32_f16(a, b, acc3[n], 0, 0, 0);
        }
    }
    int rbase = row0 + rloc;
    float dv[4];
#pragma unroll
    for (int t = 0; t < 4; ++t) {
        int gr = rbase + t;
        dv[t] = dinv[(gr < nrows) ? gr : (nrows - 1)];
    }
#pragma unroll
    for (int n = 0; n < 4; ++n) {
#pragma unroll
        for (int t = 0; t < 4; ++t) {
            int gr = rbase + t;
            if (gr >= nrows) continue;
            out[(size_t)gr * 64 + n * 16 + lm] = (_Float16)(acc3[n][t] * dv[t]);
        }
    }
}

// ---------------- launch ----------------

extern "C" void kernel_launch(void* const* d_in, const int* in_sizes, int n_in,
                              void* d_out, int out_size, void* d_ws, size_t ws_size,
                              hipStream_t stream) {
    const float* feat = (const float*)d_in[0]; // [N, 64]
    const float* W1 = (const float*)d_in[1];   // [64, 128]
    const float* b1 = (const float*)d_in[2];
    const float* W2 = (const float*)d_in[3];   // [128, 128]
    const float* b2 = (const float*)d_in[4];
    const float* W3 = (const float*)d_in[5];   // [128, 64]
    const float* b3 = (const float*)d_in[6];
    const int* ei = (const int*)d_in[7];       // [2, E]
    const int* row = ei;
    const int* col = ei + N_EDGES;
    float* out = (float*)d_out;

    // workspace bump allocator (256B aligned)
    char* ws = (char*)d_ws;
    size_t off = 0;
    auto alloc = [&](size_t bytes) {
        void* p = ws + off;
        off = alignUp(off + bytes, 256);
        return p;
    };
    constexpr size_t SLOT = (size_t)N_NODES * 128 * 2; // 12.8 MB fp16 slot
    _Float16* S1 = (_Float16*)alloc(SLOT); // featS -> X1 -> H3
    _Float16* S2 = (_Float16*)alloc(SLOT); // A1 -> A2
    float* dinv    = (float*)alloc((size_t)N_NODES * 4);
    int*   count   = (int*)alloc((size_t)N_NODES * 4);
    int*   offsets = (int*)alloc((size_t)N_NODES * 4);
    int*   rank    = (int*)alloc((size_t)N_EDGES * 4);
    int*   csr_col = (int*)alloc((size_t)(N_EDGES + 64) * 4); // +64 pad
    _Float16* W1T  = (_Float16*)alloc(128 * 64 * 2);
    _Float16* W2T  = (_Float16*)alloc(128 * 128 * 2);
    _Float16* W3T  = (_Float16*)alloc(64 * 128 * 2);

    _Float16* featS = S1; // dead after layer-1 agg
    _Float16* A1h = S2;
    _Float16* X1h = S1;   // overwrites featS
    _Float16* A2h = S2;   // overwrites A1
    _Float16* H3h = S1;   // overwrites X1 (dead after agg128)

    const int eb = (N_EDGES + 255) / 256;       // 3125
    const int cb4 = (N_EDGES / 4 + 255) / 256;  // 782
    const int gb = (N_NODES + 63) / 64;         // 782
    const int agg_grid = N_NODES / 4;           // 12500 (one node per wave)

    // 1. init: zero counters + W^T fp16 prep
    k_init<<<SCAN_BLOCKS, 256, 0, stream>>>(count, W1, W2, W3, W1T, W2T, W3T);
    // 2. degree count + per-edge rank (atomic returns)
    k_count4<<<cb4, 256, 0, stream>>>(row, count, rank, csr_col + N_EDGES);
    // 3. fused exclusive scan + dinv
    k_scan_fused<<<SCAN_BLOCKS, 256, 0, stream>>>(count, offsets, dinv);
    // 4. atomic-free scatter + fp16 feature prescale
    k_scatter<<<eb, 256, 0, stream>>>(row, col, offsets, rank, csr_col, feat, dinv, featS);
    // 5. layer-1 agg (fp16 out)
    k_agg64<false, true><<<agg_grid, 256, 0, stream>>>(featS, A1h, csr_col, offsets, count, dinv, nullptr);
    // 6. GEMM1: X1 = fp16(dinv .* relu(A1@W1+b1))
    k_gemm_mfma<64, 128, true, true, true><<<gb, 256, 0, stream>>>(A1h, W1T, b1, dinv, X1h, N_NODES);
    // 7. layer-2 agg (fp16 out)
    k_agg128<false, true><<<agg_grid, 256, 0, stream>>>(X1h, A2h, csr_col, offsets, count, dinv, nullptr);
    // 8. fused GEMM2+GEMM3: H3 = fp16(dinv .* (relu(A2@W2+b2) @ W3))
    k_gemm23<<<gb, 256, 0, stream>>>(A2h, W2T, b2, W3T, dinv, H3h, N_NODES);
    // 9. final agg + b3 -> out (fp32)
    k_agg64<true, false><<<agg_grid, 256, 0, stream>>>(H3h, out, csr_col, offsets, count, dinv, b3);
}

// Round 20
// 208.638 us; speedup vs baseline: 1.0674x; 1.0674x over previous
//
#include <hip/hip_runtime.h>

#define N_NODES 50000
#define N_EDGES 800000

#define SCAN_CHUNK 256
#define SCAN_BLOCKS ((N_NODES + SCAN_CHUNK - 1) / SCAN_CHUNK) // 196

static inline size_t alignUp(size_t x, size_t a) { return (x + a - 1) & ~(a - 1); }

// scalar-element ext vector types (R7: HIP vector classes rejected by builtins)
typedef _Float16 h2 __attribute__((ext_vector_type(2)));
typedef _Float16 h4 __attribute__((ext_vector_type(4)));
typedef _Float16 h8 __attribute__((ext_vector_type(8)));
typedef float    f4 __attribute__((ext_vector_type(4)));

// ---------------- CSR build (R14 rank-split; R16 4-edge form kept, neutral) ----

__global__ void k_zero_i32(int* __restrict__ p, int n) {
    int i = blockIdx.x * 256 + threadIdx.x;
    if (i < n) p[i] = 0;
}

__global__ void k_count4(const int* __restrict__ row, int* __restrict__ count,
                         int* __restrict__ rank, int* __restrict__ pad) {
    int i = blockIdx.x * 256 + threadIdx.x;
    if (i < 64) pad[i] = 0;
    if (i < N_EDGES / 4) {
        int4 r = reinterpret_cast<const int4*>(row)[i];
        int k0 = atomicAdd(&count[r.x], 1);
        int k1 = atomicAdd(&count[r.y], 1);
        int k2 = atomicAdd(&count[r.z], 1);
        int k3 = atomicAdd(&count[r.w], 1);
        reinterpret_cast<int4*>(rank)[i] = make_int4(k0, k1, k2, k3);
    }
}

__global__ void k_blocksum(const int* __restrict__ count, int* __restrict__ bsum) {
    __shared__ int s[256];
    int t = threadIdx.x;
    int i = blockIdx.x * 256 + t;
    int v = (i < N_NODES) ? count[i] : 0;
    s[t] = v;
    __syncthreads();
    for (int off = 128; off > 0; off >>= 1) {
        if (t < off) s[t] += s[t + off];
        __syncthreads();
    }
    if (t == 0) bsum[blockIdx.x] = s[0];
}

__global__ void k_scan_bsum(int* __restrict__ bsum) {
    __shared__ int s[256];
    int t = threadIdx.x;
    int v = (t < SCAN_BLOCKS) ? bsum[t] : 0;
    s[t] = v;
    __syncthreads();
    for (int off = 1; off < 256; off <<= 1) {
        int add = (t >= off) ? s[t - off] : 0;
        __syncthreads();
        s[t] += add;
        __syncthreads();
    }
    if (t < SCAN_BLOCKS) bsum[t] = s[t] - v; // exclusive
}

__global__ void k_scan_final(const int* __restrict__ count, const int* __restrict__ bsum,
                             int* __restrict__ offsets, float* __restrict__ dinv) {
    __shared__ int s[256];
    int t = threadIdx.x;
    int i = blockIdx.x * 256 + t;
    int v = (i < N_NODES) ? count[i] : 0;
    s[t] = v;
    __syncthreads();
    for (int off = 1; off < 256; off <<= 1) {
        int add = (t >= off) ? s[t - off] : 0;
        __syncthreads();
        s[t] += add;
        __syncthreads();
    }
    if (i < N_NODES) {
        offsets[i] = s[t] - v + bsum[blockIdx.x];
        dinv[i]    = rsqrtf((float)(v + 1)); // +1 self-loop; always > 0
    }
}

// atomic-free scatter + fused fp16 feature prescale
__global__ void k_scatter(const int* __restrict__ row, const int* __restrict__ col,
                          const int* __restrict__ offsets, const int* __restrict__ rank,
                          int* __restrict__ csr_col,
                          const float* __restrict__ feat, const float* __restrict__ dinv,
                          _Float16* __restrict__ featS) {
    int e = blockIdx.x * 256 + threadIdx.x;
    if (e < N_EDGES) {
        int node = e >> 4;
        float d = dinv[node];
        float4 v = reinterpret_cast<const float4*>(feat)[e];
        h4 hv = {(_Float16)(v.x * d), (_Float16)(v.y * d),
                 (_Float16)(v.z * d), (_Float16)(v.w * d)};
        reinterpret_cast<h4*>(featS)[e] = hv;
        int r = row[e];
        csr_col[offsets[r] + rank[e]] = col[e];
    }
}

// ---------------- weight prep: W^T fp16 (one tiny kernel, 32768 elems) ----
// W1[64][128]->W1T[128][64]; W2[128][128]->W2T[128][128]; W3[128][64]->W3T[64][128]

__global__ void k_prepw(const float* __restrict__ W1, const float* __restrict__ W2,
                        const float* __restrict__ W3, _Float16* __restrict__ W1T,
                        _Float16* __restrict__ W2T, _Float16* __restrict__ W3T) {
    int i = blockIdx.x * 256 + threadIdx.x; // 0..32767
    if (i < 8192) {
        int n = i >> 6, k = i & 63;
        W1T[i] = (_Float16)W1[k * 128 + n];
    } else if (i < 24576) {
        int j = i - 8192; int n = j >> 7, k = j & 127;
        W2T[j] = (_Float16)W2[k * 128 + n];
    } else {
        int j = i - 24576; int n = j >> 7, k = j & 127;
        W3T[j] = (_Float16)W3[k * 64 + n];
    }
}

// ---------------- Aggregation over PRE-SCALED fp16 rows ----------------
// out[i] = dinv_i * ( h'[i] + sum_c h'[c] ) (+bias); fp32 accumulate.
// HOUT: fp16 output rows (MFMA-GEMM consumers). csr_col padded (+64 zeros).

// F=128: 64 lanes x h2 = one 256B row per instruction; 8 edges per batch.
template <bool BIAS, bool HOUT>
__global__ __launch_bounds__(256) void k_agg128(const _Float16* __restrict__ hs, void* __restrict__ out,
        const int* __restrict__ csr_col, const int* __restrict__ offsets,
        const int* __restrict__ count, const float* __restrict__ dinv,
        const float* __restrict__ bias) {
    int lane = threadIdx.x & 63;
    int node = blockIdx.x * 4 + (threadIdx.x >> 6);
    const char* base = (const char*)hs;
    uint32_t lo = (uint32_t)lane << 2; // h2 byte offset within 256B row

    float ax[8], ay[8];
#pragma unroll
    for (int u = 0; u < 8; u++) { ax[u] = 0.f; ay[u] = 0.f; }

    int n = count[node];
    const int* cp = csr_col + offsets[node];

    int e = 0;
    for (; e + 8 <= n; e += 8) {
        int c[8];
#pragma unroll
        for (int u = 0; u < 8; u++) c[u] = cp[e + u];
#pragma unroll
        for (int u = 0; u < 8; u++) {
            h2 v = *reinterpret_cast<const h2*>(base + (((uint32_t)c[u] << 8) + lo));
            ax[u] += (float)v.x; ay[u] += (float)v.y;
        }
    }
    if (e < n) { // one predicated batch covers rem 1..7
        int c[8];
#pragma unroll
        for (int u = 0; u < 8; u++) c[u] = cp[e + u]; // padded, safe
#pragma unroll
        for (int u = 0; u < 8; u++) {
            h2 v = *reinterpret_cast<const h2*>(base + (((uint32_t)c[u] << 8) + lo));
            if (e + u < n) { ax[u] += (float)v.x; ay[u] += (float)v.y; }
        }
    }

    float sx = 0.f, sy = 0.f;
#pragma unroll
    for (int u = 0; u < 8; u++) { sx += ax[u]; sy += ay[u]; }
    h2 self = *reinterpret_cast<const h2*>(base + (((uint32_t)node << 8) + lo));
    float d = dinv[node];
    float ox = (sx + (float)self.x) * d, oy = (sy + (float)self.y) * d;
    if (BIAS) { ox += bias[2 * lane]; oy += bias[2 * lane + 1]; }
    if constexpr (HOUT) {
        h2 hv = {(_Float16)ox, (_Float16)oy};
        reinterpret_cast<h2*>(out)[(size_t)node * 64 + lane] = hv;
    } else {
        reinterpret_cast<float2*>(out)[(size_t)node * 64 + lane] = make_float2(ox, oy);
    }
}

// F=64: 16 lanes x h4 = one 128B row, 4 edges per instruction -> 32/batch.
template <bool BIAS, bool HOUT>
__global__ __launch_bounds__(256) void k_agg64(const _Float16* __restrict__ hs, void* __restrict__ out,
        const int* __restrict__ csr_col, const int* __restrict__ offsets,
        const int* __restrict__ count, const float* __restrict__ dinv,
        const float* __restrict__ bias) {
    int lane = threadIdx.x & 63;
    int node = blockIdx.x * 4 + (threadIdx.x >> 6);
    int q = lane >> 4;        // edge sub-slot (0..3)
    int f4 = lane & 15;       // h4 index within 128B row
    const char* base = (const char*)hs;
    uint32_t fo = (uint32_t)f4 << 3;

    int n = __builtin_amdgcn_readfirstlane(count[node]);
    int start = __builtin_amdgcn_readfirstlane(offsets[node]);
    const int* cp = csr_col + start;

    float4 a0 = make_float4(0.f, 0.f, 0.f, 0.f);
    float4 a1 = make_float4(0.f, 0.f, 0.f, 0.f);

    int e = 0;
    for (; e + 32 <= n; e += 32) {
        int c[8];
#pragma unroll
        for (int u = 0; u < 8; u++) c[u] = cp[e + 4 * u + q];
        h4 v[8];
#pragma unroll
        for (int u = 0; u < 8; u++)
            v[u] = *reinterpret_cast<const h4*>(base + (((uint32_t)c[u] << 7) + fo));
#pragma unroll
        for (int u = 0; u < 8; u += 2) {
            a0.x += (float)v[u].x; a0.y += (float)v[u].y;
            a0.z += (float)v[u].z; a0.w += (float)v[u].w;
            a1.x += (float)v[u+1].x; a1.y += (float)v[u+1].y;
            a1.z += (float)v[u+1].z; a1.w += (float)v[u+1].w;
        }
    }
    if (e < n) {
        int c[8];
#pragma unroll
        for (int u = 0; u < 8; u++) c[u] = cp[e + 4 * u + q]; // padded, safe
        h4 v[8];
#pragma unroll
        for (int u = 0; u < 8; u++)
            v[u] = *reinterpret_cast<const h4*>(base + (((uint32_t)c[u] << 7) + fo));
#pragma unroll
        for (int u = 0; u < 8; u++) {
            if (e + 4 * u + q < n) {
                a0.x += (float)v[u].x; a0.y += (float)v[u].y;
                a0.z += (float)v[u].z; a0.w += (float)v[u].w;
            }
        }
    }

    float sx = a0.x + a1.x, sy = a0.y + a1.y, sz = a0.z + a1.z, sw = a0.w + a1.w;
    sx += __shfl_xor(sx, 16); sy += __shfl_xor(sy, 16);
    sz += __shfl_xor(sz, 16); sw += __shfl_xor(sw, 16);
    sx += __shfl_xor(sx, 32); sy += __shfl_xor(sy, 32);
    sz += __shfl_xor(sz, 32); sw += __shfl_xor(sw, 32);
    if (q == 0) {
        h4 self = *reinterpret_cast<const h4*>(base + (((uint32_t)node << 7) + fo));
        float d = dinv[node];
        float ox = (sx + (float)self.x) * d, oy = (sy + (float)self.y) * d;
        float oz = (sz + (float)self.z) * d, ow = (sw + (float)self.w) * d;
        if (BIAS) {
            float4 bv = *reinterpret_cast<const float4*>(&bias[f4 * 4]);
            ox += bv.x; oy += bv.y; oz += bv.z; ow += bv.w;
        }
        if constexpr (HOUT) {
            h4 hv = {(_Float16)ox, (_Float16)oy, (_Float16)oz, (_Float16)ow};
            *reinterpret_cast<h4*>((char*)out + (((uint32_t)node << 7) + fo)) = hv;
        } else {
            *reinterpret_cast<float4*>((char*)out + ((uint32_t)node << 8) + (fo << 1)) =
                make_float4(ox, oy, oz, ow);
        }
    }
}

// ---------------- MFMA GEMM: fp16 in, fp32 accumulate ----------------
// out[r,c] = post( x[r,:] @ W[:,c] ), post = (+bias) -> relu -> (*dinv[r])
// v_mfma_f32_16x16x32_f16. Layouts per guide [m89/m91/m92]:
//   A row-major [M][K]: lane holds A[l&15][(l>>4)*8 + 0..7]  (h8, K-contig)
//   B as W^T [N][K]:    lane holds WT[l&15][(l>>4)*8 + 0..7] (h8, K-contig)
//   C/D: col = lane&15, row = (lane>>4)*4 + reg  [m89 verified]
// Wave = 16 rows x NOUT cols; block = 4 waves = 64 rows. No LDS, no barriers
// (W^T <= 32KB -> L1-resident). Grid = 782.

template <int K, int NOUT, bool RELU, bool BIAS, bool SCALE, bool HOUT>
__global__ __launch_bounds__(256) void k_gemm_mfma(const _Float16* __restrict__ x,
        const _Float16* __restrict__ WT, const float* __restrict__ bias,
        const float* __restrict__ dinv, void* __restrict__ out, int nrows) {
    constexpr int NB = NOUT / 16;
    int l = threadIdx.x & 63;
    int w = threadIdx.x >> 6;
    int lm = l & 15;
    int kb = (l >> 4) * 8; // k offset within each 32-wide k-step
    int row0 = blockIdx.x * 64 + w * 16;

    int arow = row0 + lm;
    if (arow >= nrows) arow = nrows - 1; // clamp (stores guarded below)

    f4 acc[NB] = {};

#pragma unroll
    for (int kk = 0; kk < K / 32; ++kk) {
        h8 a = *reinterpret_cast<const h8*>(x + (size_t)arow * K + kk * 32 + kb);
#pragma unroll
        for (int n = 0; n < NB; ++n) {
            h8 b = *reinterpret_cast<const h8*>(WT + (size_t)(n * 16 + lm) * K + kk * 32 + kb);
            acc[n] = __builtin_amdgcn_mfma_f32_16x16x32_f16(a, b, acc[n], 0, 0, 0);
        }
    }

    int rbase = row0 + (l >> 4) * 4;
    float dv[4];
#pragma unroll
    for (int t = 0; t < 4; ++t) {
        int gr = rbase + t;
        dv[t] = SCALE ? dinv[(gr < nrows) ? gr : (nrows - 1)] : 1.f;
    }
#pragma unroll
    for (int n = 0; n < NB; ++n) {
        float bvn = BIAS ? bias[n * 16 + lm] : 0.f;
#pragma unroll
        for (int t = 0; t < 4; ++t) {
            int gr = rbase + t;
            if (gr >= nrows) continue;
            float v = acc[n][t] + bvn;
            if (RELU) v = fmaxf(v, 0.f);
            v *= dv[t];
            if constexpr (HOUT)
                ((_Float16*)out)[(size_t)gr * NOUT + n * 16 + lm] = (_Float16)v;
            else
                ((float*)out)[(size_t)gr * NOUT + n * 16 + lm] = v;
        }
    }
}

// ---------------- launch ----------------

extern "C" void kernel_launch(void* const* d_in, const int* in_sizes, int n_in,
                              void* d_out, int out_size, void* d_ws, size_t ws_size,
                              hipStream_t stream) {
    const float* feat = (const float*)d_in[0]; // [N, 64]
    const float* W1 = (const float*)d_in[1];   // [64, 128]
    const float* b1 = (const float*)d_in[2];
    const float* W2 = (const float*)d_in[3];   // [128, 128]
    const float* b2 = (const float*)d_in[4];
    const float* W3 = (const float*)d_in[5];   // [128, 64]
    const float* b3 = (const float*)d_in[6];
    const int* ei = (const int*)d_in[7];       // [2, E]
    const int* row = ei;
    const int* col = ei + N_EDGES;
    float* out = (float*)d_out;

    // workspace bump allocator (256B aligned)
    char* ws = (char*)d_ws;
    size_t off = 0;
    auto alloc = [&](size_t bytes) {
        void* p = ws + off;
        off = alignUp(off + bytes, 256);
        return p;
    };
    constexpr size_t SLOT = (size_t)N_NODES * 128 * 2; // 12.8 MB fp16 slot
    _Float16* S1 = (_Float16*)alloc(SLOT); // featS -> X1 -> H3
    _Float16* S2 = (_Float16*)alloc(SLOT); // A1 -> A2
    _Float16* S3 = (_Float16*)alloc(SLOT); // X2
    float* dinv    = (float*)alloc((size_t)N_NODES * 4);
    int*   count   = (int*)alloc((size_t)N_NODES * 4);
    int*   offsets = (int*)alloc((size_t)N_NODES * 4);
    int*   bsum    = (int*)alloc(1024);
    int*   rank    = (int*)alloc((size_t)N_EDGES * 4);
    int*   csr_col = (int*)alloc((size_t)(N_EDGES + 64) * 4); // +64 pad
    _Float16* W1T  = (_Float16*)alloc(128 * 64 * 2);
    _Float16* W2T  = (_Float16*)alloc(128 * 128 * 2);
    _Float16* W3T  = (_Float16*)alloc(64 * 128 * 2);

    _Float16* featS = S1;
    _Float16* A1h = S2;
    _Float16* X1h = S1;
    _Float16* A2h = S2;
    _Float16* X2h = S3;
    _Float16* H3h = S1;

    const int eb = (N_EDGES + 255) / 256;       // 3125
    const int cb4 = (N_EDGES / 4 + 255) / 256;  // 782
    const int gemm_grid = (N_NODES + 63) / 64;  // 782
    const int agg_grid = N_NODES / 4;           // 12500 (one node per wave)

    // weight prep (independent of CSR chain)
    k_prepw<<<128, 256, 0, stream>>>(W1, W2, W3, W1T, W2T, W3T);

    // CSR build (every call — no cached state allowed)
    k_zero_i32<<<(N_NODES + 255) / 256, 256, 0, stream>>>(count, N_NODES);
    k_count4<<<cb4, 256, 0, stream>>>(row, count, rank, csr_col + N_EDGES);
    k_blocksum<<<SCAN_BLOCKS, 256, 0, stream>>>(count, bsum);
    k_scan_bsum<<<1, 256, 0, stream>>>(bsum);
    k_scan_final<<<SCAN_BLOCKS, 256, 0, stream>>>(count, bsum, offsets, dinv);
    k_scatter<<<eb, 256, 0, stream>>>(row, col, offsets, rank, csr_col, feat, dinv, featS);

    // Layer 1: agg (fp16 out) -> MFMA GEMM (relu+bias+scale, fp16 out)
    k_agg64<false, true><<<agg_grid, 256, 0, stream>>>(featS, A1h, csr_col, offsets, count, dinv, nullptr);
    k_gemm_mfma<64, 128, true, true, true, true><<<gemm_grid, 256, 0, stream>>>(A1h, W1T, b1, dinv, X1h, N_NODES);

    // Layer 2: agg (fp16 out) -> MFMA GEMM (relu+bias, fp16 out)
    k_agg128<false, true><<<agg_grid, 256, 0, stream>>>(X1h, A2h, csr_col, offsets, count, dinv, nullptr);
    k_gemm_mfma<128, 128, true, true, false, true><<<gemm_grid, 256, 0, stream>>>(A2h, W2T, b2, dinv, X2h, N_NODES);

    // Layer 3: MFMA GEMM (scale, fp16 out) -> agg + bias (fp32 out)
    k_gemm_mfma<128, 64, false, false, true, true><<<gemm_grid, 256, 0, stream>>>(X2h, W3T, nullptr, dinv, H3h, N_NODES);
    k_agg64<true, false><<<agg_grid, 256, 0, stream>>>(H3h, out, csr_col, offsets, count, dinv, b3);
}